// Round 4
// baseline (27.146 us; speedup 1.0000x reference)
//
#include <hip/hip_runtime.h>

#define HW_BIG   1e10f
#define LOSS_EPS 1e-8f

// ---------------------------------------------------------------------------
// distance (in pixels) to nearest set bit in a 256-bit row mask rm[4] from
// position y. Returns 32768 if the row is empty. Exact.
// ---------------------------------------------------------------------------
__device__ __forceinline__ int row_nearest(const unsigned long long* rm, int y) {
    const int yw = y >> 6, yb = y & 63;
    int dd = 32768;
    // nearest set bit at position <= y
    unsigned long long w = rm[yw] & (~0ULL >> (63 - yb));
    int j = yw;
    while (w == 0 && j > 0) w = rm[--j];
    if (w) dd = y - (j * 64 + 63 - __builtin_clzll(w));
    // nearest set bit at position >= y
    unsigned long long w2 = rm[yw] & (~0ULL << yb);
    int j2 = yw;
    while (w2 == 0 && j2 < 3) w2 = rm[++j2];
    if (w2) { int du = (j2 * 64 + __builtin_ctzll(w2)) - y; dd = min(dd, du); }
    return dd;
}

// ---------------------------------------------------------------------------
// Kernel 1: block = (img, 4-row group), 1024 threads. Builds row bitmasks:
//   rows_bib: predicted-image boundary bits   (sigmoid(v)>0.5 <=> v>0)
//   rows_blb: label boundary bits             (t>0.5)
//   rows_ml : label mask bits (t is exactly 0/1)
// Boundary rule (zero-padded 4-neighbor) computed word-parallel:
//   bnd = own & ~(up & dn & (own<<1 | carry) & (own>>1 | carry))
// Also zeroes the last-block counter for kernel 2.
// ---------------------------------------------------------------------------
__global__ void k_masks(const float* __restrict__ inp,
                        const float* __restrict__ tgt,
                        unsigned long long* __restrict__ rows_bib,
                        unsigned long long* __restrict__ rows_blb,
                        unsigned long long* __restrict__ rows_ml,
                        unsigned int* __restrict__ counter) {
    __shared__ unsigned long long V[6][4];   // 0..3 own rows, 4 up-halo, 5 down-halo
    __shared__ unsigned long long T[6][4];
    const int tid = threadIdx.x;
    const int img = blockIdx.x >> 6;
    const int r0  = (blockIdx.x & 63) * 4;
    const int r   = tid >> 8;          // 0..3
    const int y   = tid & 255;
    const int w   = y >> 6;            // word index (uniform per wave)
    const float* ip = inp + (size_t)img * 65536;
    const float* tp = tgt + (size_t)img * 65536;

    if (blockIdx.x == 0 && tid == 0) *counter = 0u;

    // own pixel
    const int x = r0 + r;
    bool vb = ip[x * 256 + y] > 0.0f;
    bool tb = tp[x * 256 + y] > 0.5f;
    unsigned long long bv = __ballot(vb);
    unsigned long long bt = __ballot(tb);
    if ((y & 63) == 0) { V[r][w] = bv; T[r][w] = bt; }

    // halo rows: waves 0-3 load row r0-1, waves 4-7 load row r0+4 (border = bg)
    if (tid < 256) {
        const int xh = r0 - 1;
        bool hv = (xh >= 0) ? (ip[xh * 256 + y] > 0.0f) : false;
        bool ht = (xh >= 0) ? (tp[xh * 256 + y] > 0.5f) : false;
        unsigned long long hbv = __ballot(hv);
        unsigned long long hbt = __ballot(ht);
        if ((y & 63) == 0) { V[4][w] = hbv; T[4][w] = hbt; }
    } else if (tid < 512) {
        const int xh = r0 + 4;
        bool hv = (xh < 256) ? (ip[xh * 256 + y] > 0.0f) : false;
        bool ht = (xh < 256) ? (tp[xh * 256 + y] > 0.5f) : false;
        unsigned long long hbv = __ballot(hv);
        unsigned long long hbt = __ballot(ht);
        if ((y & 63) == 0) { V[5][w] = hbv; T[5][w] = hbt; }
    }
    __syncthreads();

    if (tid < 32) {
        const int rr  = (tid >> 2) & 3;
        const int j   = tid & 3;
        const bool isT = tid >= 16;
        const unsigned long long (*M)[4] = isT ? T : V;
        unsigned long long own = M[rr][j];
        unsigned long long up  = (rr == 0) ? M[4][j] : M[rr - 1][j];
        unsigned long long dn  = (rr == 3) ? M[5][j] : M[rr + 1][j];
        unsigned long long lf  = (own << 1) | ((j > 0) ? (M[rr][j - 1] >> 63) : 0ULL);
        unsigned long long rt  = (own >> 1) | ((j < 3) ? (M[rr][j + 1] << 63) : 0ULL);
        unsigned long long bnd = own & ~(up & dn & lf & rt);
        const size_t o = ((size_t)img * 256 + (r0 + rr)) * 4 + j;
        if (!isT) rows_bib[o] = bnd;
        else      { rows_blb[o] = bnd; rows_ml[o] = own; }
    }
}

// ---------------------------------------------------------------------------
// Kernel 2: block = (img, 4-row group), 1024 threads. Whole-image boundary
// bitmasks (16 KB) in LDS; per pixel exact 2D nearest-boundary search with
// outward dx scan + early exit. Fused loss + deterministic reduction; the
// last block to finish does the final fixed-order double reduction.
// ---------------------------------------------------------------------------
__global__ void k_loss(const float* __restrict__ inp,
                       const unsigned long long* __restrict__ rows_bib,
                       const unsigned long long* __restrict__ rows_blb,
                       const unsigned long long* __restrict__ rows_ml,
                       float* __restrict__ partials,
                       unsigned int* __restrict__ counter,
                       float* __restrict__ out,
                       int nblk, double inv_count) {
    __shared__ unsigned long long Mib[1024];   // [row][word] image-boundary bits
    __shared__ unsigned long long Mlb[1024];   // label-boundary bits
    __shared__ float  wsum[16];
    __shared__ double dsum[8];
    __shared__ int    lastflag;
    const int tid = threadIdx.x;
    const int img = blockIdx.x >> 6;
    const int r0  = (blockIdx.x & 63) * 4;
    const int x   = r0 + (tid >> 8);
    const int y   = tid & 255;
    const int yw  = y >> 6, yb = y & 63;

    Mib[tid] = rows_bib[(size_t)img * 1024 + tid];
    Mlb[tid] = rows_blb[(size_t)img * 1024 + tid];
    const float v = inp[((size_t)img * 256 + x) * 256 + y];
    const float t = ((rows_ml[(size_t)img * 1024 + x * 4 + yw] >> yb) & 1) ? 1.0f : 0.0f;
    __syncthreads();

    const bool fib = (Mib[x * 4 + yw] >> yb) & 1;
    const bool flb = (Mlb[x * 4 + yw] >> yb) & 1;

    // best1: d^2 to image boundary (consumed only where flb)
    // best2: d^2 to label boundary (consumed only where fib)
    int best1 = 0, best2 = 0;
    if (flb) { int d = row_nearest(&Mib[x * 4], y); best1 = d * d; }
    if (fib) { int d = row_nearest(&Mlb[x * 4], y); best2 = d * d; }
    if (flb | fib) {
        for (int dx = 1; dx < 256; ++dx) {
            const int dx2 = dx * dx;
            if (dx2 >= best1 && dx2 >= best2) break;
            const int xu = x - dx, xd = x + dx;
            if (xu >= 0) {
                if (dx2 < best1) { int d = row_nearest(&Mib[xu * 4], y); best1 = min(best1, dx2 + d * d); }
                if (dx2 < best2) { int d = row_nearest(&Mlb[xu * 4], y); best2 = min(best2, dx2 + d * d); }
            }
            if (xd < 256) {
                if (dx2 < best1) { int d = row_nearest(&Mib[xd * 4], y); best1 = min(best1, dx2 + d * d); }
                if (dx2 < best2) { int d = row_nearest(&Mlb[xd * 4], y); best2 = min(best2, dx2 + d * d); }
            }
        }
    }
    const float m1 = (best1 >= (1 << 29)) ? HW_BIG : (float)best1;
    const float m2 = (best2 >= (1 << 29)) ? HW_BIG : (float)best2;

    const float p = 1.0f / (1.0f + expf(-v));
    float wgt = 1.0f;
    if (flb) wgt += expf(-sqrtf(m1));   // THETA=1, SIGMA=1
    if (fib) wgt += expf(-sqrtf(m2));

    // GAMMA = 1
    float loss = wgt * (-(1.0f - p) * t * logf(p + LOSS_EPS)
                        - p * (1.0f - t) * logf(1.0f - p + LOSS_EPS));

    // deterministic block reduction (fixed order)
    float s = loss;
#pragma unroll
    for (int off = 32; off > 0; off >>= 1) s += __shfl_down(s, off, 64);
    if ((tid & 63) == 0) wsum[tid >> 6] = s;
    __syncthreads();
    if (tid == 0) {
        float bs = 0.0f;
#pragma unroll
        for (int i = 0; i < 16; ++i) bs += wsum[i];
        partials[blockIdx.x] = bs;
        __threadfence();                         // release partials
        unsigned int old = atomicAdd(counter, 1u);
        lastflag = (old == (unsigned int)(nblk - 1)) ? 1 : 0;
    }
    __syncthreads();

    if (lastflag) {
        __threadfence();                         // acquire all partials
        if (tid < 512) {
            double ds = (tid < nblk) ? (double)partials[tid] : 0.0;
#pragma unroll
            for (int off = 32; off > 0; off >>= 1) ds += __shfl_down(ds, off, 64);
            if ((tid & 63) == 0) dsum[tid >> 6] = ds;
        }
        __syncthreads();
        if (tid == 0) {
            double tot = 0.0;
#pragma unroll
            for (int i = 0; i < 8; ++i) tot += dsum[i];
            out[0] = (float)(tot * inv_count);
        }
    }
}

// ---------------------------------------------------------------------------
extern "C" void kernel_launch(void* const* d_in, const int* in_sizes, int n_in,
                              void* d_out, int out_size, void* d_ws, size_t ws_size,
                              hipStream_t stream) {
    const float* inp = (const float*)d_in[0];
    const float* tgt = (const float*)d_in[1];
    float* out = (float*)d_out;

    const int total = in_sizes[0];          // B*256*256
    const int nimg  = total / 65536;        // B = 8
    const int nblk  = nimg * 64;            // 512 blocks of 1024 threads

    char* ws = (char*)d_ws;
    unsigned long long* rows_bib = (unsigned long long*)ws;            // nimg*1024 u64
    unsigned long long* rows_blb = rows_bib + (size_t)nimg * 1024;
    unsigned long long* rows_ml  = rows_blb + (size_t)nimg * 1024;
    float*              parts    = (float*)(rows_ml + (size_t)nimg * 1024);
    unsigned int*       counter  = (unsigned int*)(parts + nblk);

    k_masks<<<nblk, 1024, 0, stream>>>(inp, tgt, rows_bib, rows_blb, rows_ml, counter);
    k_loss <<<nblk, 1024, 0, stream>>>(inp, rows_bib, rows_blb, rows_ml,
                                       parts, counter, out, nblk, 1.0 / (double)total);
}